// Round 11
// baseline (228.097 us; speedup 1.0000x reference)
//
#include <hip/hip_runtime.h>
#include <cstdint>
#include <cstddef>

// ---------------------------------------------------------------------------
// Types / helpers
// ---------------------------------------------------------------------------
typedef __attribute__((ext_vector_type(8)))  __bf16 bf16x8;
typedef __attribute__((ext_vector_type(4)))  float  f32x4;
typedef __attribute__((ext_vector_type(16))) float  f32x16;
typedef __attribute__((ext_vector_type(8)))  unsigned short us8;

#define MFMA(a, b, c)   __builtin_amdgcn_mfma_f32_16x16x32_bf16((a), (b), (c), 0, 0, 0)
#define MFMA32(a, b, c) __builtin_amdgcn_mfma_f32_32x32x16_bf16((a), (b), (c), 0, 0, 0)

// 0.125 (=Hd^-0.5) * log2(e): folded into Q so scores come out in log2 domain
#define QSCALE 0.18033688011112042f

__device__ __forceinline__ unsigned short f2bf(float f) {
  unsigned u = __float_as_uint(f);
  u += 0x7fffu + ((u >> 16) & 1u);          // round-to-nearest-even
  return (unsigned short)(u >> 16);
}

__device__ __forceinline__ float bf2f(unsigned short s) {
  unsigned u = ((unsigned)s) << 16;
  return __uint_as_float(u);
}

// pack two f32 -> one u32 of 2 bf16, low word = first arg. Single VALU op;
// numerically equivalent to the explicit round-half-up pack (PROVEN: rounds
// 2 and 3 produced bit-identical absmax with cvt_pk vs explicit pack).
__device__ __forceinline__ unsigned cvtpk(float lo, float hi) {
  unsigned r;
  asm("v_cvt_pk_bf16_f32 %0, %1, %2" : "=v"(r) : "v"(lo), "v"(hi));
  return r;
}

// v_permlane32_swap_b32 semantics pinned by r1(fail)/r4(pass)/r7(pass) A/B:
//   pl32swap(a=X0, b=X1) ->
//     a' = {lo: own X0, hi: partner(lane-32)'s X1}
//     b' = {lo: partner(+32)'s X0, hi: own X1}
__device__ __forceinline__ void pl32swap(unsigned& a, unsigned& b) {
  asm("v_permlane32_swap_b32 %0, %1" : "+v"(a), "+v"(b));
}

// async global -> LDS, 16 B per lane. LDS dest = wave-uniform base + lane*16.
__device__ __forceinline__ void gload16(const void* g, void* l) {
  __builtin_amdgcn_global_load_lds(
      (__attribute__((address_space(1))) unsigned int*)(uintptr_t)g,
      (__attribute__((address_space(3))) unsigned int*)l,
      16, 0, 0);
}

// depth-4 tree sum of 16 floats (explicit reassociation; no serial chain)
__device__ __forceinline__ float tree16(const float* p) {
  float a = (p[0] + p[1]) + (p[2] + p[3]);
  float b = (p[4] + p[5]) + (p[6] + p[7]);
  float c = (p[8] + p[9]) + (p[10] + p[11]);
  float d = (p[12] + p[13]) + (p[14] + p[15]);
  return (a + b) + (c + d);
}

// ---------------------------------------------------------------------------
// fp32 -> bf16 cast, WEIGHTS ONLY now (q/k/v cast fused into proj_qkv).
// 4 x 65536 float4 segments.
// ---------------------------------------------------------------------------
struct CastArgs {
  const float*    src[4];
  unsigned short* dst[4];
};
__global__ __launch_bounds__(256) void cast_kernel(CastArgs a) {
  const int i = blockIdx.x * 256 + threadIdx.x;    // 0 .. 262143
  const int z = i >> 16, off = i & 65535;
  float4 f = ((const float4*)a.src[z])[off];
  ushort4 r;
  r.x = f2bf(f.x); r.y = f2bf(f.y); r.z = f2bf(f.z); r.w = f2bf(f.w);
  ((ushort4*)a.dst[z])[off] = r;
}

// ---------------------------------------------------------------------------
// QKV projection with FUSED input cast:
//   C[m,n] = (sum_k X_f32[m,k] * W[n,k] + bias[n]) * scl
// X read directly as fp32 (reg-stage -> cvtpk -> swizzled ds_write; the old
// standalone cast kernel's 48MB round-trip + serializing dependency gone).
// W via gload16, 3 LDS buffers, 2-deep prefetch. Wait accounting identical
// to proj_out (validated r9): consuming the A regs retires all older VMEM,
// so only the newest W pair (2 ops) can be outstanding -> vmcnt(2).
// z=0 (Q): scl=QSCALE, out [bh][t][hd]; z=1 (K): same layout, scl=1;
// z=2 (V): out transposed [bh][hd][t] via LDS-transposed epilogue.
// ---------------------------------------------------------------------------
struct ProjArgs {
  const float*          Xf[3];
  const unsigned short* W[3];
  const float*          bias[3];
  unsigned short*       out[3];
};

__global__ __launch_bounds__(256) void proj_qkv_kernel(ProjArgs args) {
  // sA: 2 bufs x [128][32]; sB: 3 bufs x [128][32]  (40 KB total)
  // z=2 epilogue reuses smem[0..8703] as 64 x 136 transpose buffer.
  __shared__ alignas(16) unsigned short smem[20480];
  unsigned short* sAb[2] = {smem, smem + 4096};
  unsigned short* sBb[3] = {smem + 8192, smem + 12288, smem + 16384};

  const int z = blockIdx.z;
  const float* __restrict__ Xf           = args.Xf[z];
  const unsigned short* __restrict__ W   = args.W[z];
  const float* __restrict__ bias         = args.bias[z];
  unsigned short* __restrict__ out       = args.out[z];
  const float scl = (z == 0) ? QSCALE : 1.0f;

  const int t = threadIdx.x;
  const int w = t >> 6, lane = t & 63;
  const int quad = lane >> 4, l15 = lane & 15;
  const int wr = w >> 1, wc = w & 1;
  const int m0 = blockIdx.x * 128, n0 = blockIdx.y * 128;

  const int arow = t >> 2, ac = t & 3;              // A staging: row, chunk
  const int axc  = (ac ^ (arow & 3)) << 3;          // source fp32 col offset
  const int srow = t >> 2;                          // B staging (gload16)
  const int scol = (((t & 3) ^ (srow & 3)) << 3);

  f32x4 acc[4][4] = {};

#define LOADX(va, vb, vc, vd, kk)                                              \
  {                                                                            \
    const float* p0 = Xf + (size_t)(m0 + arow) * 512 + (kk) + axc;             \
    const float* p1 = Xf + (size_t)(m0 + arow + 64) * 512 + (kk) + axc;        \
    va = *(const float4*)p0; vb = *(const float4*)(p0 + 4);                    \
    vc = *(const float4*)p1; vd = *(const float4*)(p1 + 4);                    \
  }
#define WRITEX(buf, va, vb, vc, vd)                                            \
  {                                                                            \
    unsigned o0[4] = {cvtpk(va.x, va.y), cvtpk(va.z, va.w),                    \
                      cvtpk(vb.x, vb.y), cvtpk(vb.z, vb.w)};                   \
    unsigned o1[4] = {cvtpk(vc.x, vc.y), cvtpk(vc.z, vc.w),                    \
                      cvtpk(vd.x, vd.y), cvtpk(vd.z, vd.w)};                   \
    *(us8*)&sAb[buf][arow * 32 + (ac << 3)] = *(us8*)o0;                       \
    *(us8*)&sAb[buf][(arow + 64) * 32 + (ac << 3)] = *(us8*)o1;                \
  }
#define LOADW(idx, kk)                                                         \
  {                                                                            \
    gload16(W + (size_t)(n0 + srow) * 512 + (kk) + scol,      &sBb[idx][w * 512]); \
    gload16(W + (size_t)(n0 + srow + 64) * 512 + (kk) + scol, &sBb[idx][2048 + w * 512]); \
  }

  // prologue: A(0) -> sA[0]; W(0) -> sB[0]; W(32) -> sB[1]
  {
    float4 va, vb, vc, vd;
    LOADX(va, vb, vc, vd, 0);
    WRITEX(0, va, vb, vc, vd);
    LOADW(0, 0);
    LOADW(1, 32);
  }
  __syncthreads();

#pragma unroll
  for (int k0 = 0; k0 < 512; k0 += 32) {
    const int ba = (k0 >> 5) & 1;
    const int bb = (k0 >> 5) % 3;

    float4 va, vb, vc, vd;
    if (k0 < 480) LOADX(va, vb, vc, vd, k0 + 32);
    if (k0 < 448) LOADW((bb + 2) % 3, k0 + 64);

    bf16x8 af[4], bfr[4];
#pragma unroll
    for (int mt = 0; mt < 4; ++mt) {
      int ra = wr * 64 + mt * 16 + l15;
      af[mt] = *(const bf16x8*)&sAb[ba][ra * 32 + ((quad ^ (ra & 3)) << 3)];
    }
#pragma unroll
    for (int nt = 0; nt < 4; ++nt) {
      int rb = wc * 64 + nt * 16 + l15;
      bfr[nt] = *(const bf16x8*)&sBb[bb][rb * 32 + ((quad ^ (rb & 3)) << 3)];
    }
#pragma unroll
    for (int mt = 0; mt < 4; ++mt)
#pragma unroll
      for (int nt = 0; nt < 4; ++nt)
        acc[mt][nt] = MFMA(af[mt], bfr[nt], acc[mt][nt]);

    if (k0 < 480) WRITEX(ba ^ 1, va, vb, vc, vd);

    // consuming A regs retired all older VMEM; only newest W pair remains
    asm volatile("s_waitcnt vmcnt(2) lgkmcnt(0)" ::: "memory");
    __builtin_amdgcn_s_barrier();
  }
#undef LOADX
#undef WRITEX
#undef LOADW

  if (z != 2) {
#pragma unroll
    for (int nt = 0; nt < 4; ++nt) {
      int n = n0 + wc * 64 + nt * 16 + l15;
      float bv = bias[n];
      int h = n >> 6, hd = n & 63;
#pragma unroll
      for (int mt = 0; mt < 4; ++mt) {
#pragma unroll
        for (int r = 0; r < 4; ++r) {
          int m = m0 + wr * 64 + mt * 16 + quad * 4 + r;
          int b = m >> 12, tt = m & 4095;
          out[(((size_t)(b * 8 + h)) * 4096 + tt) * 64 + hd] =
              f2bf((acc[mt][nt][r] + bv) * scl);
        }
      }
    }
  } else {
    const int b   = m0 >> 12;
    const int tt0 = m0 & 4095;
#pragma unroll
    for (int h2 = 0; h2 < 2; ++h2) {
      __syncthreads();
      if (wc == h2) {
#pragma unroll
        for (int nt = 0; nt < 4; ++nt) {
          int nl = nt * 16 + l15;
          float bv = bias[n0 + h2 * 64 + nl];
#pragma unroll
          for (int mt = 0; mt < 4; ++mt)
#pragma unroll
            for (int r = 0; r < 4; ++r) {
              int ml = wr * 64 + mt * 16 + quad * 4 + r;
              smem[nl * 136 + ml] = f2bf((acc[mt][nt][r] + bv) * scl);
            }
        }
      }
      __syncthreads();
      const int row = t >> 2;
      const int c4  = (t & 3) * 8;
      const int n   = n0 + h2 * 64 + row;
      unsigned short* dst = out + ((size_t)(b * 512 + n)) * 4096 + tt0;
#pragma unroll
      for (int k = 0; k < 4; ++k)
        *(us8*)(dst + c4 + k * 32) = *(const us8*)&smem[row * 136 + c4 + k * 32];
    }
  }
}

// ---------------------------------------------------------------------------
// Output projection FUSED with flash-decoding combine (validated r9/r10):
//   out[m,n] = sum_k A[m,k]*Wo[n,k] + bo[n],  A = (pO0+pO1)*invL
// W: 3 LDS buffers, 2-deep gload16 prefetch; A: 1-deep reg prefetch + cvt +
// swizzled ds_write; counted end-of-iter wait vmcnt(2).
// ---------------------------------------------------------------------------
__global__ __launch_bounds__(256) void proj_out_kernel(
    const unsigned short* __restrict__ P0, const unsigned short* __restrict__ P1,
    const float* __restrict__ pL, const unsigned short* __restrict__ W,
    const float* __restrict__ bias, float* __restrict__ out) {
  __shared__ alignas(16) unsigned short sA[2][2048];   // [buf][64 x 32] swz
  __shared__ alignas(16) unsigned short sB[3][4096];   // [buf][128 x 32] swz
  __shared__ float invL[512];                          // [h][row]

  const int t = threadIdx.x;
  const int w = t >> 6, lane = t & 63;
  const int quad = lane >> 4, l15 = lane & 15;
  const int m0 = blockIdx.x * 64, n0 = blockIdx.y * 128;
  const int b  = m0 >> 12, tt0 = m0 & 4095;   // block never crosses batch

  // per-block normalizers: invL[h*64+row] = 1/(lA+lB) for row t = tt0+row
  {
    const int hh = t >> 5;            // 0..7
    const int r2 = (t & 31) * 2;
#pragma unroll
    for (int i = 0; i < 2; ++i) {
      const int row = r2 + i;
      const size_t ix = (size_t)(b * 8 + hh) * 4096 + tt0 + row;
      invL[hh * 64 + row] = 1.0f / (pL[ix] + pL[65536 + ix]);
    }
  }

  const int arow = t >> 2, ac = t & 3;              // A staging: row, chunk
  const int srow = t >> 2;                          // B staging (gload16)
  const int scol = (((t & 3) ^ (srow & 3)) << 3);

  __syncthreads();                                  // invL visible

  // prologue: A(0) -> sA[0]; W(0) -> sB[0]; W(32) -> sB[1]
  {
    us8 a0 = *(const us8*)&P0[(size_t)(m0 + arow) * 512 + ac * 8];
    us8 a1 = *(const us8*)&P1[(size_t)(m0 + arow) * 512 + ac * 8];
    const float inv = invL[arow];                   // h = 0 for k < 32
    unsigned o[4];
#pragma unroll
    for (int i = 0; i < 4; ++i)
      o[i] = cvtpk((bf2f(a0[2 * i]) + bf2f(a1[2 * i])) * inv,
                   (bf2f(a0[2 * i + 1]) + bf2f(a1[2 * i + 1])) * inv);
    *(us8*)&sA[0][arow * 32 + ((ac ^ (arow & 3)) << 3)] = *(us8*)o;
    gload16(W + (size_t)(n0 + srow) * 512 + scol,      &sB[0][w * 512]);
    gload16(W + (size_t)(n0 + srow + 64) * 512 + scol, &sB[0][2048 + w * 512]);
    gload16(W + (size_t)(n0 + srow) * 512 + 32 + scol,      &sB[1][w * 512]);
    gload16(W + (size_t)(n0 + srow + 64) * 512 + 32 + scol, &sB[1][2048 + w * 512]);
  }
  __syncthreads();

  f32x4 acc[4][2] = {};

#pragma unroll
  for (int k0 = 0; k0 < 512; k0 += 32) {
    const int ba = (k0 >> 5) & 1;
    const int bb = (k0 >> 5) % 3;

    // A(k+1) reg loads first (older than W issues -> consumption retires all)
    us8 a0n = {}, a1n = {};
    float invn = 0.f;
    if (k0 < 480) {
      const int kn = k0 + 32;
      a0n = *(const us8*)&P0[(size_t)(m0 + arow) * 512 + kn + ac * 8];
      a1n = *(const us8*)&P1[(size_t)(m0 + arow) * 512 + kn + ac * 8];
      invn = invL[(kn >> 6) * 64 + arow];           // h uniform per k-step
    }
    if (k0 < 448) {
      const int kn2 = k0 + 64;
      gload16(W + (size_t)(n0 + srow) * 512 + kn2 + scol,      &sB[(bb + 2) % 3][w * 512]);
      gload16(W + (size_t)(n0 + srow + 64) * 512 + kn2 + scol, &sB[(bb + 2) % 3][2048 + w * 512]);
    }

    // compute current buffers (prefetch latency hides under this)
    bf16x8 af[4], bfr[2];
#pragma unroll
    for (int mt = 0; mt < 4; ++mt) {
      int ra = mt * 16 + l15;
      af[mt] = *(const bf16x8*)&sA[ba][ra * 32 + ((quad ^ (ra & 3)) << 3)];
    }
#pragma unroll
    for (int nt = 0; nt < 2; ++nt) {
      int rb = w * 32 + nt * 16 + l15;
      bfr[nt] = *(const bf16x8*)&sB[bb][rb * 32 + ((quad ^ (rb & 3)) << 3)];
    }
#pragma unroll
    for (int mt = 0; mt < 4; ++mt)
#pragma unroll
      for (int nt = 0; nt < 2; ++nt)
        acc[mt][nt] = MFMA(af[mt], bfr[nt], acc[mt][nt]);

    if (k0 < 480) {
      unsigned o[4];
#pragma unroll
      for (int i = 0; i < 4; ++i)
        o[i] = cvtpk((bf2f(a0n[2 * i]) + bf2f(a1n[2 * i])) * invn,
                     (bf2f(a0n[2 * i + 1]) + bf2f(a1n[2 * i + 1])) * invn);
      *(us8*)&sA[ba ^ 1][arow * 32 + ((ac ^ (arow & 3)) << 3)] = *(us8*)o;
    }

    // W(k+1) already retired (older than consumed A); only W(k+2) may remain
    asm volatile("s_waitcnt vmcnt(2) lgkmcnt(0)" ::: "memory");
    __builtin_amdgcn_s_barrier();
  }

#pragma unroll
  for (int nt = 0; nt < 2; ++nt) {
    int n = n0 + w * 32 + nt * 16 + l15;
    float bv = bias[n];
#pragma unroll
    for (int mt = 0; mt < 4; ++mt) {
#pragma unroll
      for (int r = 0; r < 4; ++r) {
        int m = m0 + mt * 16 + quad * 4 + r;
        out[(size_t)m * 512 + n] = acc[mt][nt][r] + bv;
      }
    }
  }
}

// ---------------------------------------------------------------------------
// Flash attention, QBLK=64/wave + 2-way KV-split — exact r9 structure
// (setprio REVERTED: measured −5.5us regression in r10).
// ---------------------------------------------------------------------------
__global__ __launch_bounds__(128, 2) void attn_kernel(
    const unsigned short* __restrict__ Q, const unsigned short* __restrict__ K,
    const unsigned short* __restrict__ VT,
    unsigned short* __restrict__ pO0, unsigned short* __restrict__ pO1,
    float* __restrict__ pL) {
  __shared__ alignas(16) unsigned short kt[2][4096];  // [buf][s=64][d=64] swz
  __shared__ alignas(16) unsigned short vt[2][4096];  // [buf][d=64][s=64] swz

  const int t = threadIdx.x;            // 0..127
  const int w = t >> 6;                 // 0..1
  const int lane = t & 63;
  const int l31 = lane & 31, h = lane >> 5;

  // bijective XCD swizzle over 1024 blocks
  const int wg  = blockIdx.x + gridDim.x * blockIdx.y;     // 0..1023
  const int swz = (wg & 7) * 128 + (wg >> 3);
  const int qt  = swz & 31;
  const int bh2 = swz >> 5;
  const int bh  = bh2 & 15, half = bh2 >> 4;

  const unsigned short* __restrict__ Qp  = Q  + (size_t)bh * 4096 * 64;
  const unsigned short* __restrict__ Kp  = K  + (size_t)bh * 4096 * 64;
  const unsigned short* __restrict__ VTp = VT + (size_t)bh * 64 * 4096;

  const int q0w = qt * 128 + w * 64;
  const int sbase = half * 2048;

  const int lr   = lane >> 3;                            // 0..7
  const int gcol = (((lane & 7) ^ lr) << 3);             // source chunk swz

#define STAGE(bbuf, s0)                                                        \
  {                                                                            \
    _Pragma("unroll")                                                          \
    for (int i = 0; i < 4; ++i)                                                \
      gload16(Kp + (size_t)((s0) + w * 32 + i * 8 + lr) * 64 + gcol,           \
              &kt[bbuf][(w * 32 + i * 8) * 64]);                               \
    _Pragma("unroll")                                                          \
    for (int i = 0; i < 4; ++i)                                                \
      gload16(VTp + (size_t)(w * 32 + i * 8 + lr) * 4096 + (s0) + gcol,        \
              &vt[bbuf][(w * 32 + i * 8) * 64]);                               \
  }

  STAGE(0, sbase);

  bf16x8 aqA[4], aqB[4];
#pragma unroll
  for (int kd = 0; kd < 4; ++kd) {
    aqA[kd] = *(const bf16x8*)(Qp + (size_t)(q0w + l31) * 64 + kd * 16 + h * 8);
    aqB[kd] = *(const bf16x8*)(Qp + (size_t)(q0w + 32 + l31) * 64 + kd * 16 + h * 8);
  }

  f32x16 o0a = {}, o1a = {}, o0b = {}, o1b = {};
  float lia = 0.f, lib = 0.f;

  const int swzk = l31 & 7;

  for (int j = 0; j < 32; ++j) {
    const int cb = j & 1, nb = cb ^ 1;
    if (j < 31) {
      STAGE(nb, sbase + (j + 1) * 64);
      asm volatile("s_waitcnt vmcnt(8)" ::: "memory");
    } else {
      asm volatile("s_waitcnt vmcnt(0)" ::: "memory");
    }
    __builtin_amdgcn_s_barrier();
    asm volatile("" ::: "memory");

    const unsigned short* ktb = kt[cb];
    const unsigned short* vtb = vt[cb];

#pragma unroll
    for (int st = 0; st < 2; ++st) {
      bf16x8 kf[4];
#pragma unroll
      for (int kd = 0; kd < 4; ++kd)
        kf[kd] = *(const bf16x8*)&ktb[(st * 32 + l31) * 64 +
                                      (((2 * kd + h) ^ swzk) << 3)];
      f32x16 sa = {}, sb = {};
#pragma unroll
      for (int kd = 0; kd < 4; ++kd) {
        sa = MFMA32(kf[kd], aqA[kd], sa);
        sb = MFMA32(kf[kd], aqB[kd], sb);
      }

      float pA[16], pB[16];
#pragma unroll
      for (int r = 0; r < 16; ++r) {
        pA[r] = __builtin_amdgcn_exp2f(sa[r]);
        pB[r] = __builtin_amdgcn_exp2f(sb[r]);
      }
      lia += tree16(pA);
      lib += tree16(pB);

      unsigned XgA[4], YgA[4], XgB[4], YgB[4];
#pragma unroll
      for (int g = 0; g < 4; ++g) {
        XgA[g] = cvtpk(pA[4 * g + 0], pA[4 * g + 1]);
        YgA[g] = cvtpk(pA[4 * g + 2], pA[4 * g + 3]);
        XgB[g] = cvtpk(pB[4 * g + 0], pB[4 * g + 1]);
        YgB[g] = cvtpk(pB[4 * g + 2], pB[4 * g + 3]);
      }

#pragma unroll
      for (int ks = 0; ks < 2; ++ks) {
        const int c = st * 4 + 2 * ks + h;
        bf16x8 v0 = *(const bf16x8*)&vtb[l31 * 64 + ((c ^ swzk) << 3)];
        bf16x8 v1 = *(const bf16x8*)&vtb[(l31 + 32) * 64 + ((c ^ swzk) << 3)];

        unsigned a0 = XgA[2 * ks], a2 = XgA[2 * ks + 1];
        unsigned a1 = YgA[2 * ks], a3 = YgA[2 * ks + 1];
        pl32swap(a0, a2);
        pl32swap(a1, a3);
        union { unsigned u[4]; bf16x8 v; } paA;
        paA.u[0] = a0; paA.u[1] = a1; paA.u[2] = a2; paA.u[3] = a3;
        o0a = MFMA32(paA.v, v0, o0a);
        o1a = MFMA32(paA.v, v1, o1a);

        unsigned b0 = XgB[2 * ks], b2 = XgB[2 * ks + 1];
        unsigned b1 = YgB[2 * ks], b3 = YgB[2 * ks + 1];
        pl32swap(b0, b2);
        pl32swap(b1, b3);
        union { unsigned u[4]; bf16x8 v; } paB;
        paB.u[0] = b0; paB.u[1] = b1; paB.u[2] = b2; paB.u[3] = b3;
        o0b = MFMA32(paB.v, v0, o0b);
        o1b = MFMA32(paB.v, v1, o1b);
      }
    }

    asm volatile("" ::: "memory");
    __builtin_amdgcn_s_barrier();
  }
#undef STAGE

  lia += __shfl_xor(lia, 32, 64);
  lib += __shfl_xor(lib, 32, 64);
  float* __restrict__ PLh = pL + half * 65536 + bh * 4096;
  if (h == 0) {
    PLh[q0w + l31]      = lia;
    PLh[q0w + 32 + l31] = lib;
  }

  unsigned short* __restrict__ PO = half ? pO1 : pO0;
  const int bq = bh >> 3, hh = bh & 7;
#pragma unroll
  for (int r = 0; r < 16; ++r) {
    const int qloc = (r & 3) + 8 * (r >> 2) + 4 * h;
    const size_t baseA = ((size_t)bq * 4096 + q0w + qloc) * 512 + hh * 64;
    PO[baseA + l31]      = f2bf(o0a[r]);
    PO[baseA + 32 + l31] = f2bf(o1a[r]);
    const size_t baseB = ((size_t)bq * 4096 + q0w + 32 + qloc) * 512 + hh * 64;
    PO[baseB + l31]      = f2bf(o0b[r]);
    PO[baseB + 32 + l31] = f2bf(o1b[r]);
  }
}

// ---------------------------------------------------------------------------
// launch
// ---------------------------------------------------------------------------
extern "C" void kernel_launch(void* const* d_in, const int* in_sizes, int n_in,
                              void* d_out, int out_size, void* d_ws, size_t ws_size,
                              hipStream_t stream) {
  (void)in_sizes; (void)n_in; (void)out_size; (void)ws_size;
  const float* query = (const float*)d_in[0];
  const float* key_  = (const float*)d_in[1];
  const float* value = (const float*)d_in[2];
  const float* Wq = (const float*)d_in[3];
  const float* bq = (const float*)d_in[4];
  const float* Wk = (const float*)d_in[5];
  const float* bk = (const float*)d_in[6];
  const float* Wv = (const float*)d_in[7];
  const float* bv = (const float*)d_in[8];
  const float* Wo = (const float*)d_in[9];
  const float* bo = (const float*)d_in[10];
  float* out = (float*)d_out;

  char* ws = (char*)d_ws;
  const size_t MB = 1024 * 1024;
  unsigned short* Wqb = (unsigned short*)(ws + 24 * MB);
  unsigned short* Wkb = (unsigned short*)(ws + 24 * MB + 512 * 1024);
  unsigned short* Wvb = (unsigned short*)(ws + 25 * MB);
  unsigned short* Wob = (unsigned short*)(ws + 58 * MB);  // 512 KB
  // live through attn:
  unsigned short* qb  = (unsigned short*)(ws + 26 * MB);  // 8 MB
  unsigned short* kb  = (unsigned short*)(ws + 34 * MB);  // 8 MB
  unsigned short* vtb = (unsigned short*)(ws + 42 * MB);  // 16 MB, V^T
  // attn partials:
  unsigned short* pO0 = (unsigned short*)(ws + 0 * MB);   // 8 MB bf16
  unsigned short* pO1 = (unsigned short*)(ws + 9 * MB);   // 8 MB bf16
  float*          pL  = (float*)(ws + 18 * MB);           // 2x65536 fp32

  CastArgs ca;
  ca.src[0] = Wq;  ca.src[1] = Wk;  ca.src[2] = Wv;  ca.src[3] = Wo;
  ca.dst[0] = Wqb; ca.dst[1] = Wkb; ca.dst[2] = Wvb; ca.dst[3] = Wob;
  cast_kernel<<<dim3(1024), 256, 0, stream>>>(ca);

  ProjArgs pa;
  pa.Xf[0] = query; pa.Xf[1] = key_; pa.Xf[2] = value;
  pa.W[0] = Wqb; pa.W[1] = Wkb; pa.W[2] = Wvb;
  pa.bias[0] = bq; pa.bias[1] = bk; pa.bias[2] = bv;
  pa.out[0] = qb; pa.out[1] = kb; pa.out[2] = vtb;
  proj_qkv_kernel<<<dim3(64, 4, 3), 256, 0, stream>>>(pa);

  attn_kernel<<<dim3(32, 32), 128, 0, stream>>>(qb, kb, vtb, pO0, pO1, pL);

  proj_out_kernel<<<dim3(128, 4), 256, 0, stream>>>(pO0, pO1, pL, Wob, bo, out);
}

// Round 12
// 217.270 us; speedup vs baseline: 1.0498x; 1.0498x over previous
//
#include <hip/hip_runtime.h>
#include <cstdint>
#include <cstddef>

// ---------------------------------------------------------------------------
// Types / helpers
// ---------------------------------------------------------------------------
typedef __attribute__((ext_vector_type(8)))  __bf16 bf16x8;
typedef __attribute__((ext_vector_type(4)))  float  f32x4;
typedef __attribute__((ext_vector_type(16))) float  f32x16;
typedef __attribute__((ext_vector_type(8)))  unsigned short us8;

#define MFMA(a, b, c)   __builtin_amdgcn_mfma_f32_16x16x32_bf16((a), (b), (c), 0, 0, 0)
#define MFMA32(a, b, c) __builtin_amdgcn_mfma_f32_32x32x16_bf16((a), (b), (c), 0, 0, 0)

// 0.125 (=Hd^-0.5) * log2(e): folded into Q so scores come out in log2 domain
#define QSCALE 0.18033688011112042f

__device__ __forceinline__ unsigned short f2bf(float f) {
  unsigned u = __float_as_uint(f);
  u += 0x7fffu + ((u >> 16) & 1u);          // round-to-nearest-even
  return (unsigned short)(u >> 16);
}

__device__ __forceinline__ float bf2f(unsigned short s) {
  unsigned u = ((unsigned)s) << 16;
  return __uint_as_float(u);
}

// pack two f32 -> one u32 of 2 bf16, low word = first arg (1 VALU op; proven
// numerically identical to explicit round-half-up pack in r2/r3).
__device__ __forceinline__ unsigned cvtpk(float lo, float hi) {
  unsigned r;
  asm("v_cvt_pk_bf16_f32 %0, %1, %2" : "=v"(r) : "v"(lo), "v"(hi));
  return r;
}

// v_permlane32_swap_b32 semantics pinned by r1(fail)/r4(pass)/r7(pass) A/B:
//   pl32swap(a=X0, b=X1) ->
//     a' = {lo: own X0, hi: partner(lane-32)'s X1}
//     b' = {lo: partner(+32)'s X0, hi: own X1}
__device__ __forceinline__ void pl32swap(unsigned& a, unsigned& b) {
  asm("v_permlane32_swap_b32 %0, %1" : "+v"(a), "+v"(b));
}

// async global -> LDS, 16 B per lane. LDS dest = wave-uniform base + lane*16.
__device__ __forceinline__ void gload16(const void* g, void* l) {
  __builtin_amdgcn_global_load_lds(
      (__attribute__((address_space(1))) unsigned int*)(uintptr_t)g,
      (__attribute__((address_space(3))) unsigned int*)l,
      16, 0, 0);
}

// depth-4 tree sum of 16 floats (explicit reassociation; no serial chain)
__device__ __forceinline__ float tree16(const float* p) {
  float a = (p[0] + p[1]) + (p[2] + p[3]);
  float b = (p[4] + p[5]) + (p[6] + p[7]);
  float c = (p[8] + p[9]) + (p[10] + p[11]);
  float d = (p[12] + p[13]) + (p[14] + p[15]);
  return (a + b) + (c + d);
}

// ---------------------------------------------------------------------------
// fp32 -> bf16 cast, all 7 tensors, exact flat grid (no empty blocks).
// Segments: 3 x 1048576 float4 (q/k/v) then 4 x 65536 (weights).
// [r11 lesson: fusing the X-cast into proj_qkv loses — X is re-read by 4
//  n-blocks, so fp32-in-the-GEMM doubles traffic AND adds in-loop VALU;
//  the standalone cast amortizes conversion across one read.]
// ---------------------------------------------------------------------------
struct CastArgs {
  const float*    src[7];
  unsigned short* dst[7];
};
__global__ __launch_bounds__(256) void cast_kernel(CastArgs a) {
  const int i = blockIdx.x * 256 + threadIdx.x;    // 0 .. 3407871
  int z, off;
  if (i < 3145728) { z = i >> 20;            off = i & 1048575; }
  else             { int j = i - 3145728; z = 3 + (j >> 16); off = j & 65535; }
  float4 f = ((const float4*)a.src[z])[off];
  ushort4 r;
  r.x = f2bf(f.x); r.y = f2bf(f.y); r.z = f2bf(f.z); r.w = f2bf(f.w);
  ((ushort4*)a.dst[z])[off] = r;
}

// ---------------------------------------------------------------------------
// QKV projection: C[m,n] = (sum_k X[m,k] * W[n,k] + bias[n]) * scl
// z=0 (Q): scl=QSCALE, out [bh][t][hd]
// z=1 (K): scl=1,      out [bh][t][hd]
// z=2 (V): scl=1,      out TRANSPOSED [bh][hd][t] via LDS-transposed epilogue.
// K-loop: THREE LDS buffers, 2-tile-deep gload16 prefetch (vmcnt(8) steady
// state) — best measured config (r10, non-attn 129.6us).
// ---------------------------------------------------------------------------
struct ProjArgs {
  const unsigned short* X[3];
  const unsigned short* W[3];
  const float*          bias[3];
  unsigned short*       out[3];
};

__global__ __launch_bounds__(256) void proj_qkv_kernel(ProjArgs args) {
  __shared__ alignas(16) unsigned short smem[3 * 8192];   // 48 KB

  const int z = blockIdx.z;
  const unsigned short* __restrict__ X   = args.X[z];
  const unsigned short* __restrict__ W   = args.W[z];
  const float* __restrict__ bias         = args.bias[z];
  unsigned short* __restrict__ out       = args.out[z];
  const float scl = (z == 0) ? QSCALE : 1.0f;

  const int t = threadIdx.x;
  const int w = t >> 6, lane = t & 63;
  const int quad = lane >> 4, l15 = lane & 15;
  const int wr = w >> 1, wc = w & 1;
  const int m0 = blockIdx.x * 128, n0 = blockIdx.y * 128;

  const int srow = t >> 2;                              // 0..63
  const int scol = (((t & 3) ^ (srow & 3)) << 3);       // swizzled source chunk

  f32x4 acc[4][4] = {};

#define STAGEP(idx, kk)                                                        \
  {                                                                            \
    unsigned short* nA = smem + (idx) * 8192;                                  \
    unsigned short* nB = nA + 4096;                                            \
    gload16(X + (size_t)(m0 + srow) * 512 + (kk) + scol,      &nA[w * 512]);   \
    gload16(X + (size_t)(m0 + srow + 64) * 512 + (kk) + scol, &nA[2048 + w * 512]); \
    gload16(W + (size_t)(n0 + srow) * 512 + (kk) + scol,      &nB[w * 512]);   \
    gload16(W + (size_t)(n0 + srow + 64) * 512 + (kk) + scol, &nB[2048 + w * 512]); \
  }

  // prologue: two tiles in flight
  STAGEP(0, 0);
  STAGEP(1, 32);

#pragma unroll
  for (int k0 = 0; k0 < 512; k0 += 32) {
    const int bi = (k0 >> 5) % 3;
    unsigned short* sA = smem + bi * 8192;
    unsigned short* sB = sA + 4096;
    if (k0 < 448) {
      STAGEP((bi + 2) % 3, k0 + 64);
      asm volatile("s_waitcnt vmcnt(8)" ::: "memory");   // current tile landed
    } else if (k0 == 448) {
      asm volatile("s_waitcnt vmcnt(4)" ::: "memory");
    } else {
      asm volatile("s_waitcnt vmcnt(0)" ::: "memory");
    }
    __builtin_amdgcn_s_barrier();
    asm volatile("" ::: "memory");

    bf16x8 af[4], bfr[4];
#pragma unroll
    for (int mt = 0; mt < 4; ++mt) {
      int ra = wr * 64 + mt * 16 + l15;
      af[mt] = *(const bf16x8*)&sA[ra * 32 + ((quad ^ (ra & 3)) << 3)];
    }
#pragma unroll
    for (int nt = 0; nt < 4; ++nt) {
      int rb = wc * 64 + nt * 16 + l15;
      bfr[nt] = *(const bf16x8*)&sB[rb * 32 + ((quad ^ (rb & 3)) << 3)];
    }
#pragma unroll
    for (int mt = 0; mt < 4; ++mt)
#pragma unroll
      for (int nt = 0; nt < 4; ++nt)
        acc[mt][nt] = MFMA(af[mt], bfr[nt], acc[mt][nt]);

    asm volatile("" ::: "memory");
    __builtin_amdgcn_s_barrier();     // reads done before buf is overwritten
  }
#undef STAGEP

  if (z != 2) {
#pragma unroll
    for (int nt = 0; nt < 4; ++nt) {
      int n = n0 + wc * 64 + nt * 16 + l15;
      float bv = bias[n];
      int h = n >> 6, hd = n & 63;
#pragma unroll
      for (int mt = 0; mt < 4; ++mt) {
#pragma unroll
        for (int r = 0; r < 4; ++r) {
          int m = m0 + wr * 64 + mt * 16 + quad * 4 + r;
          int b = m >> 12, tt = m & 4095;
          out[(((size_t)(b * 8 + h)) * 4096 + tt) * 64 + hd] =
              f2bf((acc[mt][nt][r] + bv) * scl);
        }
      }
    }
  } else {
    const int b   = m0 >> 12;
    const int tt0 = m0 & 4095;
#pragma unroll
    for (int h2 = 0; h2 < 2; ++h2) {
      __syncthreads();
      if (wc == h2) {
#pragma unroll
        for (int nt = 0; nt < 4; ++nt) {
          int nl = nt * 16 + l15;
          float bv = bias[n0 + h2 * 64 + nl];
#pragma unroll
          for (int mt = 0; mt < 4; ++mt)
#pragma unroll
            for (int r = 0; r < 4; ++r) {
              int ml = wr * 64 + mt * 16 + quad * 4 + r;
              smem[nl * 136 + ml] = f2bf((acc[mt][nt][r] + bv) * scl);
            }
        }
      }
      __syncthreads();
      const int row = t >> 2;
      const int c4  = (t & 3) * 8;
      const int n   = n0 + h2 * 64 + row;
      unsigned short* dst = out + ((size_t)(b * 512 + n)) * 4096 + tt0;
#pragma unroll
      for (int k = 0; k < 4; ++k)
        *(us8*)(dst + c4 + k * 32) = *(const us8*)&smem[row * 136 + c4 + k * 32];
    }
  }
}

// ---------------------------------------------------------------------------
// Output projection FUSED with flash-decoding combine (validated r9/r10):
//   out[m,n] = sum_k A[m,k]*Wo[n,k] + bo[n],  A = (pO0+pO1)*invL
// W: 3 LDS buffers, 2-deep gload16 prefetch; A: 1-deep reg prefetch + cvt +
// swizzled ds_write; counted end-of-iter wait vmcnt(2).
// ---------------------------------------------------------------------------
__global__ __launch_bounds__(256) void proj_out_kernel(
    const unsigned short* __restrict__ P0, const unsigned short* __restrict__ P1,
    const float* __restrict__ pL, const unsigned short* __restrict__ W,
    const float* __restrict__ bias, float* __restrict__ out) {
  __shared__ alignas(16) unsigned short sA[2][2048];   // [buf][64 x 32] swz
  __shared__ alignas(16) unsigned short sB[3][4096];   // [buf][128 x 32] swz
  __shared__ float invL[512];                          // [h][row]

  const int t = threadIdx.x;
  const int w = t >> 6, lane = t & 63;
  const int quad = lane >> 4, l15 = lane & 15;
  const int m0 = blockIdx.x * 64, n0 = blockIdx.y * 128;
  const int b  = m0 >> 12, tt0 = m0 & 4095;   // block never crosses batch

  // per-block normalizers: invL[h*64+row] = 1/(lA+lB) for row t = tt0+row
  {
    const int hh = t >> 5;            // 0..7
    const int r2 = (t & 31) * 2;
#pragma unroll
    for (int i = 0; i < 2; ++i) {
      const int row = r2 + i;
      const size_t ix = (size_t)(b * 8 + hh) * 4096 + tt0 + row;
      invL[hh * 64 + row] = 1.0f / (pL[ix] + pL[65536 + ix]);
    }
  }

  const int arow = t >> 2, ac = t & 3;              // A staging: row, chunk
  const int srow = t >> 2;                          // B staging (gload16)
  const int scol = (((t & 3) ^ (srow & 3)) << 3);

  __syncthreads();                                  // invL visible

  // prologue: A(0) -> sA[0]; W(0) -> sB[0]; W(32) -> sB[1]
  {
    us8 a0 = *(const us8*)&P0[(size_t)(m0 + arow) * 512 + ac * 8];
    us8 a1 = *(const us8*)&P1[(size_t)(m0 + arow) * 512 + ac * 8];
    const float inv = invL[arow];                   // h = 0 for k < 32
    unsigned o[4];
#pragma unroll
    for (int i = 0; i < 4; ++i)
      o[i] = cvtpk((bf2f(a0[2 * i]) + bf2f(a1[2 * i])) * inv,
                   (bf2f(a0[2 * i + 1]) + bf2f(a1[2 * i + 1])) * inv);
    *(us8*)&sA[0][arow * 32 + ((ac ^ (arow & 3)) << 3)] = *(us8*)o;
    gload16(W + (size_t)(n0 + srow) * 512 + scol,      &sB[0][w * 512]);
    gload16(W + (size_t)(n0 + srow + 64) * 512 + scol, &sB[0][2048 + w * 512]);
    gload16(W + (size_t)(n0 + srow) * 512 + 32 + scol,      &sB[1][w * 512]);
    gload16(W + (size_t)(n0 + srow + 64) * 512 + 32 + scol, &sB[1][2048 + w * 512]);
  }
  __syncthreads();

  f32x4 acc[4][2] = {};

#pragma unroll
  for (int k0 = 0; k0 < 512; k0 += 32) {
    const int ba = (k0 >> 5) & 1;
    const int bb = (k0 >> 5) % 3;

    // A(k+1) reg loads first (older than W issues -> consumption retires all)
    us8 a0n = {}, a1n = {};
    float invn = 0.f;
    if (k0 < 480) {
      const int kn = k0 + 32;
      a0n = *(const us8*)&P0[(size_t)(m0 + arow) * 512 + kn + ac * 8];
      a1n = *(const us8*)&P1[(size_t)(m0 + arow) * 512 + kn + ac * 8];
      invn = invL[(kn >> 6) * 64 + arow];           // h uniform per k-step
    }
    if (k0 < 448) {
      const int kn2 = k0 + 64;
      gload16(W + (size_t)(n0 + srow) * 512 + kn2 + scol,      &sB[(bb + 2) % 3][w * 512]);
      gload16(W + (size_t)(n0 + srow + 64) * 512 + kn2 + scol, &sB[(bb + 2) % 3][2048 + w * 512]);
    }

    // compute current buffers (prefetch latency hides under this)
    bf16x8 af[4], bfr[2];
#pragma unroll
    for (int mt = 0; mt < 4; ++mt) {
      int ra = mt * 16 + l15;
      af[mt] = *(const bf16x8*)&sA[ba][ra * 32 + ((quad ^ (ra & 3)) << 3)];
    }
#pragma unroll
    for (int nt = 0; nt < 2; ++nt) {
      int rb = w * 32 + nt * 16 + l15;
      bfr[nt] = *(const bf16x8*)&sB[bb][rb * 32 + ((quad ^ (rb & 3)) << 3)];
    }
#pragma unroll
    for (int mt = 0; mt < 4; ++mt)
#pragma unroll
      for (int nt = 0; nt < 2; ++nt)
        acc[mt][nt] = MFMA(af[mt], bfr[nt], acc[mt][nt]);

    if (k0 < 480) {
      unsigned o[4];
#pragma unroll
      for (int i = 0; i < 4; ++i)
        o[i] = cvtpk((bf2f(a0n[2 * i]) + bf2f(a1n[2 * i])) * invn,
                     (bf2f(a0n[2 * i + 1]) + bf2f(a1n[2 * i + 1])) * invn);
      *(us8*)&sA[ba ^ 1][arow * 32 + ((ac ^ (arow & 3)) << 3)] = *(us8*)o;
    }

    // W(k+1) already retired (older than consumed A); only W(k+2) may remain
    asm volatile("s_waitcnt vmcnt(2) lgkmcnt(0)" ::: "memory");
    __builtin_amdgcn_s_barrier();
  }

#pragma unroll
  for (int nt = 0; nt < 2; ++nt) {
    int n = n0 + w * 32 + nt * 16 + l15;
    float bv = bias[n];
#pragma unroll
    for (int mt = 0; mt < 4; ++mt) {
#pragma unroll
      for (int r = 0; r < 4; ++r) {
        int m = m0 + mt * 16 + quad * 4 + r;
        out[(size_t)m * 512 + n] = acc[mt][nt][r] + bv;
      }
    }
  }
}

// ---------------------------------------------------------------------------
// Flash attention, QBLK=64/wave + 2-way KV-split — exact r9 structure
// (no setprio: r10 A/B measured it a −5.5us regression on this schedule).
// ---------------------------------------------------------------------------
__global__ __launch_bounds__(128, 2) void attn_kernel(
    const unsigned short* __restrict__ Q, const unsigned short* __restrict__ K,
    const unsigned short* __restrict__ VT,
    unsigned short* __restrict__ pO0, unsigned short* __restrict__ pO1,
    float* __restrict__ pL) {
  __shared__ alignas(16) unsigned short kt[2][4096];  // [buf][s=64][d=64] swz
  __shared__ alignas(16) unsigned short vt[2][4096];  // [buf][d=64][s=64] swz

  const int t = threadIdx.x;            // 0..127
  const int w = t >> 6;                 // 0..1
  const int lane = t & 63;
  const int l31 = lane & 31, h = lane >> 5;

  // bijective XCD swizzle over 1024 blocks
  const int wg  = blockIdx.x + gridDim.x * blockIdx.y;     // 0..1023
  const int swz = (wg & 7) * 128 + (wg >> 3);
  const int qt  = swz & 31;
  const int bh2 = swz >> 5;
  const int bh  = bh2 & 15, half = bh2 >> 4;

  const unsigned short* __restrict__ Qp  = Q  + (size_t)bh * 4096 * 64;
  const unsigned short* __restrict__ Kp  = K  + (size_t)bh * 4096 * 64;
  const unsigned short* __restrict__ VTp = VT + (size_t)bh * 64 * 4096;

  const int q0w = qt * 128 + w * 64;
  const int sbase = half * 2048;

  const int lr   = lane >> 3;                            // 0..7
  const int gcol = (((lane & 7) ^ lr) << 3);             // source chunk swz

#define STAGE(bbuf, s0)                                                        \
  {                                                                            \
    _Pragma("unroll")                                                          \
    for (int i = 0; i < 4; ++i)                                                \
      gload16(Kp + (size_t)((s0) + w * 32 + i * 8 + lr) * 64 + gcol,           \
              &kt[bbuf][(w * 32 + i * 8) * 64]);                               \
    _Pragma("unroll")                                                          \
    for (int i = 0; i < 4; ++i)                                                \
      gload16(VTp + (size_t)(w * 32 + i * 8 + lr) * 4096 + (s0) + gcol,        \
              &vt[bbuf][(w * 32 + i * 8) * 64]);                               \
  }

  STAGE(0, sbase);

  bf16x8 aqA[4], aqB[4];
#pragma unroll
  for (int kd = 0; kd < 4; ++kd) {
    aqA[kd] = *(const bf16x8*)(Qp + (size_t)(q0w + l31) * 64 + kd * 16 + h * 8);
    aqB[kd] = *(const bf16x8*)(Qp + (size_t)(q0w + 32 + l31) * 64 + kd * 16 + h * 8);
  }

  f32x16 o0a = {}, o1a = {}, o0b = {}, o1b = {};
  float lia = 0.f, lib = 0.f;

  const int swzk = l31 & 7;

  for (int j = 0; j < 32; ++j) {
    const int cb = j & 1, nb = cb ^ 1;
    if (j < 31) {
      STAGE(nb, sbase + (j + 1) * 64);
      asm volatile("s_waitcnt vmcnt(8)" ::: "memory");
    } else {
      asm volatile("s_waitcnt vmcnt(0)" ::: "memory");
    }
    __builtin_amdgcn_s_barrier();
    asm volatile("" ::: "memory");

    const unsigned short* ktb = kt[cb];
    const unsigned short* vtb = vt[cb];

#pragma unroll
    for (int st = 0; st < 2; ++st) {
      bf16x8 kf[4];
#pragma unroll
      for (int kd = 0; kd < 4; ++kd)
        kf[kd] = *(const bf16x8*)&ktb[(st * 32 + l31) * 64 +
                                      (((2 * kd + h) ^ swzk) << 3)];
      f32x16 sa = {}, sb = {};
#pragma unroll
      for (int kd = 0; kd < 4; ++kd) {
        sa = MFMA32(kf[kd], aqA[kd], sa);
        sb = MFMA32(kf[kd], aqB[kd], sb);
      }

      float pA[16], pB[16];
#pragma unroll
      for (int r = 0; r < 16; ++r) {
        pA[r] = __builtin_amdgcn_exp2f(sa[r]);
        pB[r] = __builtin_amdgcn_exp2f(sb[r]);
      }
      lia += tree16(pA);
      lib += tree16(pB);

      unsigned XgA[4], YgA[4], XgB[4], YgB[4];
#pragma unroll
      for (int g = 0; g < 4; ++g) {
        XgA[g] = cvtpk(pA[4 * g + 0], pA[4 * g + 1]);
        YgA[g] = cvtpk(pA[4 * g + 2], pA[4 * g + 3]);
        XgB[g] = cvtpk(pB[4 * g + 0], pB[4 * g + 1]);
        YgB[g] = cvtpk(pB[4 * g + 2], pB[4 * g + 3]);
      }

#pragma unroll
      for (int ks = 0; ks < 2; ++ks) {
        const int c = st * 4 + 2 * ks + h;
        bf16x8 v0 = *(const bf16x8*)&vtb[l31 * 64 + ((c ^ swzk) << 3)];
        bf16x8 v1 = *(const bf16x8*)&vtb[(l31 + 32) * 64 + ((c ^ swzk) << 3)];

        unsigned a0 = XgA[2 * ks], a2 = XgA[2 * ks + 1];
        unsigned a1 = YgA[2 * ks], a3 = YgA[2 * ks + 1];
        pl32swap(a0, a2);
        pl32swap(a1, a3);
        union { unsigned u[4]; bf16x8 v; } paA;
        paA.u[0] = a0; paA.u[1] = a1; paA.u[2] = a2; paA.u[3] = a3;
        o0a = MFMA32(paA.v, v0, o0a);
        o1a = MFMA32(paA.v, v1, o1a);

        unsigned b0 = XgB[2 * ks], b2 = XgB[2 * ks + 1];
        unsigned b1 = YgB[2 * ks], b3 = YgB[2 * ks + 1];
        pl32swap(b0, b2);
        pl32swap(b1, b3);
        union { unsigned u[4]; bf16x8 v; } paB;
        paB.u[0] = b0; paB.u[1] = b1; paB.u[2] = b2; paB.u[3] = b3;
        o0b = MFMA32(paB.v, v0, o0b);
        o1b = MFMA32(paB.v, v1, o1b);
      }
    }

    asm volatile("" ::: "memory");
    __builtin_amdgcn_s_barrier();
  }
#undef STAGE

  lia += __shfl_xor(lia, 32, 64);
  lib += __shfl_xor(lib, 32, 64);
  float* __restrict__ PLh = pL + half * 65536 + bh * 4096;
  if (h == 0) {
    PLh[q0w + l31]      = lia;
    PLh[q0w + 32 + l31] = lib;
  }

  unsigned short* __restrict__ PO = half ? pO1 : pO0;
  const int bq = bh >> 3, hh = bh & 7;
#pragma unroll
  for (int r = 0; r < 16; ++r) {
    const int qloc = (r & 3) + 8 * (r >> 2) + 4 * h;
    const size_t baseA = ((size_t)bq * 4096 + q0w + qloc) * 512 + hh * 64;
    PO[baseA + l31]      = f2bf(o0a[r]);
    PO[baseA + 32 + l31] = f2bf(o1a[r]);
    const size_t baseB = ((size_t)bq * 4096 + q0w + 32 + qloc) * 512 + hh * 64;
    PO[baseB + l31]      = f2bf(o0b[r]);
    PO[baseB + 32 + l31] = f2bf(o1b[r]);
  }
}

// ---------------------------------------------------------------------------
// launch
// ---------------------------------------------------------------------------
extern "C" void kernel_launch(void* const* d_in, const int* in_sizes, int n_in,
                              void* d_out, int out_size, void* d_ws, size_t ws_size,
                              hipStream_t stream) {
  (void)in_sizes; (void)n_in; (void)out_size; (void)ws_size;
  const float* query = (const float*)d_in[0];
  const float* key_  = (const float*)d_in[1];
  const float* value = (const float*)d_in[2];
  const float* Wq = (const float*)d_in[3];
  const float* bq = (const float*)d_in[4];
  const float* Wk = (const float*)d_in[5];
  const float* bk = (const float*)d_in[6];
  const float* Wv = (const float*)d_in[7];
  const float* bv = (const float*)d_in[8];
  const float* Wo = (const float*)d_in[9];
  const float* bo = (const float*)d_in[10];
  float* out = (float*)d_out;

  char* ws = (char*)d_ws;
  const size_t MB = 1024 * 1024;
  // phase 1-2 regions (dead after proj_qkv):
  unsigned short* Xq  = (unsigned short*)(ws + 0 * MB);   // 8 MB
  unsigned short* Xk  = (unsigned short*)(ws + 8 * MB);   // 8 MB
  unsigned short* Xv  = (unsigned short*)(ws + 16 * MB);  // 8 MB
  unsigned short* Wqb = (unsigned short*)(ws + 24 * MB);
  unsigned short* Wkb = (unsigned short*)(ws + 24 * MB + 512 * 1024);
  unsigned short* Wvb = (unsigned short*)(ws + 25 * MB);
  // live through attn:
  unsigned short* qb  = (unsigned short*)(ws + 26 * MB);  // 8 MB
  unsigned short* kb  = (unsigned short*)(ws + 34 * MB);  // 8 MB
  unsigned short* vtb = (unsigned short*)(ws + 42 * MB);  // 16 MB, V^T
  unsigned short* Wob = (unsigned short*)(ws + 58 * MB);  // 512 KB
  // attn partials (overwrite dead Xq/Xk/Xv):
  unsigned short* pO0 = (unsigned short*)(ws + 0 * MB);   // 8 MB bf16
  unsigned short* pO1 = (unsigned short*)(ws + 9 * MB);   // 8 MB bf16
  float*          pL  = (float*)(ws + 18 * MB);           // 2x65536 fp32

  CastArgs ca;
  ca.src[0] = query; ca.src[1] = key_; ca.src[2] = value;
  ca.src[3] = Wq;    ca.src[4] = Wk;   ca.src[5] = Wv;  ca.src[6] = Wo;
  ca.dst[0] = Xq;    ca.dst[1] = Xk;   ca.dst[2] = Xv;
  ca.dst[3] = Wqb;   ca.dst[4] = Wkb;  ca.dst[5] = Wvb; ca.dst[6] = Wob;
  cast_kernel<<<dim3(13312), 256, 0, stream>>>(ca);

  ProjArgs pa;
  pa.X[0] = Xq;  pa.X[1] = Xk;  pa.X[2] = Xv;
  pa.W[0] = Wqb; pa.W[1] = Wkb; pa.W[2] = Wvb;
  pa.bias[0] = bq; pa.bias[1] = bk; pa.bias[2] = bv;
  pa.out[0] = qb; pa.out[1] = kb; pa.out[2] = vtb;
  proj_qkv_kernel<<<dim3(64, 4, 3), 256, 0, stream>>>(pa);

  attn_kernel<<<dim3(32, 32), 128, 0, stream>>>(qb, kb, vtb, pO0, pO1, pL);

  proj_out_kernel<<<dim3(128, 4), 256, 0, stream>>>(pO0, pO1, pL, Wob, bo, out);
}